// Round 11
// baseline (46.082 us; speedup 1.0000x reference)
//
#include <hip/hip_runtime.h>
#include <math.h>

#define NB 1024
#define NC 64
#define NH 64
#define ND 256
#define NHID 256

typedef float f4 __attribute__((ext_vector_type(4)));

// ws layout (floats): [0..255] = v_h, [256] = mask mode (int),
// [1024 .. 1024+64*256) = P1 partials (needs ws >= 69,632 B)
#define WS_PART_OFF 1024

// Raw barrier with LDS-only drain: DS ops complete, global loads/stores stay
// in flight across the barrier (__syncthreads would drain vmcnt(0)).
#define BAR_LGKM() asm volatile("s_waitcnt lgkmcnt(0)\n\ts_barrier" ::: "memory")

// mask storage modes: 0 = int32, 1 = byte (bool), 2 = float32
__device__ __forceinline__ bool read_mask(const void* m, int idx, int mode) {
  if (mode == 2) return ((const float*)m)[idx] != 0.0f;
  if (mode == 1) return ((const unsigned char*)m)[idx] != 0;
  return ((const int*)m)[idx] != 0;
}

__device__ __forceinline__ void detect_mode(const unsigned int* mask_cand,
                                            const unsigned int* mask_hist,
                                            int* dst) {
  int sawf = 0; unsigned int big = 0;
  for (int i = 0; i < 32; ++i) {
    unsigned int a = mask_hist[i], b = mask_cand[i];
    if (a == 0x3f800000u || b == 0x3f800000u) sawf = 1;
    if ((a > 1u && a != 0x3f800000u) || (b > 1u && b != 0x3f800000u)) big = 1;
  }
  *dst = sawf ? 2 : (big ? 1 : 0);
}

__device__ __forceinline__ float dot4(f4 a, f4 b) {
  return fmaf(a.x, b.x, fmaf(a.y, b.y, fmaf(a.z, b.z, a.w * b.w)));
}

#define BFLY(p) { p += __shfl_xor(p, 32); p += __shfl_xor(p, 16); p += __shfl_xor(p, 8); \
                  p += __shfl_xor(p, 4);  p += __shfl_xor(p, 2);  p += __shfl_xor(p, 1); }

// ---- P1: 64 blocks x 256 threads: partial v_h over 4 j-rows each ----
__global__ __launch_bounds__(256) void precompute_p1(
    const float* __restrict__ W1, const float* __restrict__ W2,
    float* __restrict__ ws)
{
  const int g = blockIdx.x;
  const int d = threadIdx.x;
  float acc = 0.f;
  #pragma unroll
  for (int jj = 0; jj < 4; ++jj) {
    int j = g * 4 + jj;
    acc = fmaf(W1[(size_t)j * (2 * ND) + ND + d], W2[j], acc);
  }
  ws[WS_PART_OFF + g * ND + d] = acc;
}

// ---- P2: 1 block x 256 threads: reduce partials, detect mask mode ----
__global__ __launch_bounds__(256) void precompute_p2(
    const unsigned int* __restrict__ mask_cand,
    const unsigned int* __restrict__ mask_hist,
    float* __restrict__ ws)
{
  const int d = threadIdx.x;
  float acc = 0.f;
  #pragma unroll 8
  for (int g = 0; g < 64; ++g) acc += ws[WS_PART_OFF + g * ND + d];
  ws[d] = acc;
  if (d == 0) detect_mode(mask_cand, mask_hist, (int*)ws + ND);
}

// ---- fallback single-block precompute (small ws) ----
__global__ __launch_bounds__(1024) void precompute_fallback(
    const float* __restrict__ W1, const float* __restrict__ W2,
    const unsigned int* __restrict__ mask_cand,
    const unsigned int* __restrict__ mask_hist,
    float* __restrict__ ws)
{
  __shared__ float w2_lds[NHID];
  __shared__ float partial[4][ND];
  int t = threadIdx.x;
  if (t < NHID) w2_lds[t] = W2[t];
  __syncthreads();
  int d = t & (ND - 1);
  int g = t >> 8;
  float acc = 0.f;
  #pragma unroll 8
  for (int j = g * 64; j < g * 64 + 64; ++j)
    acc = fmaf(W1[(size_t)j * (2 * ND) + ND + d], w2_lds[j], acc);
  partial[g][d] = acc;
  __syncthreads();
  if (t < ND)
    ws[t] = partial[0][t] + partial[1][t] + partial[2][t] + partial[3][t];
  if (t == 0) detect_mode(mask_cand, mask_hist, (int*)ws + ND);
}

// Load 8 rows of batch BB into named f4 regs (each instr = 64x16B = 1 KB)
#define LOAD8(R0,R1,R2,R3,R4,R5,R6,R7, BB)                                     \
  {                                                                            \
    const f4* hp_ = reinterpret_cast<const f4*>(hist) + (size_t)(BB) * 4096;   \
    R0 = hp_[(w * 8 + 0) * 64 + lane]; R1 = hp_[(w * 8 + 1) * 64 + lane];      \
    R2 = hp_[(w * 8 + 2) * 64 + lane]; R3 = hp_[(w * 8 + 3) * 64 + lane];      \
    R4 = hp_[(w * 8 + 4) * 64 + lane]; R5 = hp_[(w * 8 + 5) * 64 + lane];      \
    R6 = hp_[(w * 8 + 6) * 64 + lane]; R7 = hp_[(w * 8 + 7) * 64 + lane];      \
  }

// Full per-batch processing: scores -> softmax -> weighted sum -> store.
// MHV: per-lane (lane<8) hist-mask bit; MCB: wave-uniform 8-bit cand mask.
#define PROC(X0,X1,X2,X3,X4,X5,X6,X7, BC, MHV, MCB)                            \
  {                                                                            \
    float p0 = dot4(X0, vh), p1 = dot4(X1, vh), p2 = dot4(X2, vh),             \
          p3 = dot4(X3, vh), p4 = dot4(X4, vh), p5 = dot4(X5, vh),             \
          p6 = dot4(X6, vh), p7 = dot4(X7, vh);                                \
    BFLY(p0) BFLY(p1) BFLY(p2) BFLY(p3) BFLY(p4) BFLY(p5) BFLY(p6) BFLY(p7)    \
    if (lane < 8) {                                                            \
      float v_ = p0;                                                           \
      if (lane == 1) v_ = p1;  if (lane == 2) v_ = p2;  if (lane == 3) v_ = p3;\
      if (lane == 4) v_ = p4;  if (lane == 5) v_ = p5;  if (lane == 6) v_ = p6;\
      if (lane == 7) v_ = p7;                                                  \
      s_lds[w * 8 + lane] = (MHV) ? v_ : -3.0e38f;                             \
    }                                                                          \
    BAR_LGKM();                                                                \
    float wval_;                                                               \
    {                                                                          \
      float s_ = s_lds[lane];                                                  \
      float m_ = s_;                                                           \
      m_ = fmaxf(m_, __shfl_xor(m_, 32)); m_ = fmaxf(m_, __shfl_xor(m_, 16));  \
      m_ = fmaxf(m_, __shfl_xor(m_, 8));  m_ = fmaxf(m_, __shfl_xor(m_, 4));   \
      m_ = fmaxf(m_, __shfl_xor(m_, 2));  m_ = fmaxf(m_, __shfl_xor(m_, 1));   \
      float e_ = expf(s_ - m_);                                                \
      float sum_ = e_; BFLY(sum_)                                              \
      wval_ = e_ / sum_;                                                       \
    }                                                                          \
    {                                                                          \
      f4 acc_ = __shfl(wval_, w * 8 + 0) * X0;                                 \
      acc_ += __shfl(wval_, w * 8 + 1) * X1;                                   \
      acc_ += __shfl(wval_, w * 8 + 2) * X2;                                   \
      acc_ += __shfl(wval_, w * 8 + 3) * X3;                                   \
      acc_ += __shfl(wval_, w * 8 + 4) * X4;                                   \
      acc_ += __shfl(wval_, w * 8 + 5) * X5;                                   \
      acc_ += __shfl(wval_, w * 8 + 6) * X6;                                   \
      acc_ += __shfl(wval_, w * 8 + 7) * X7;                                   \
      red[w][lane] = acc_;                                                     \
    }                                                                          \
    BAR_LGKM();                                                                \
    {                                                                          \
      f4 uv_ = red[0][lane];                                                   \
      _Pragma("unroll")                                                        \
      for (int q_ = 1; q_ < 8; ++q_) uv_ += red[q_][lane];                     \
      f4* ob4_ = reinterpret_cast<f4*>(out) + (size_t)(BC) * 4096;             \
      _Pragma("unroll")                                                        \
      for (int j_ = 0; j_ < 8; ++j_) {                                         \
        int c_ = w * 8 + j_;                                                   \
        ob4_[c_ * 64 + lane] = (((MCB) >> j_) & 1u) ? uv_ : zero;              \
      }                                                                        \
    }                                                                          \
  }

// ---- main: 256 blocks x 512 threads (1 block/CU); block handles 4
// consecutive batches with a 1-ahead register double-buffer pipeline, so
// each wave alternates load-issue / store-issue continuously (fill-kernel
// regime) instead of one-shot bursts. lgkm-only barriers keep global
// traffic flowing across them. ----
__global__ __launch_bounds__(512, 4) void fused4_kernel(
    const float* __restrict__ hist,
    const void* __restrict__ mask_cand_v,
    const void* __restrict__ mask_hist_v,
    const float* __restrict__ ws,
    float* __restrict__ out)
{
  const int t = threadIdx.x, lane = t & 63, w = t >> 6;
  const int b0 = blockIdx.x * 4;
  __shared__ float s_lds[NH];
  __shared__ f4 red[8][64];                      // 8 KB

  const int mode = ((const int*)ws)[ND];
  const f4 vh = reinterpret_cast<const f4*>(ws)[lane];   // 1 KB, L1-hot
  const f4 zero = {0.f, 0.f, 0.f, 0.f};

  f4 x0, x1, x2, x3, x4, x5, x6, x7;
  f4 y0, y1, y2, y3, y4, y5, y6, y7;

  // prologue: batches b0 and b0+1 in flight
  LOAD8(x0,x1,x2,x3,x4,x5,x6,x7, b0 + 0);
  LOAD8(y0,y1,y2,y3,y4,y5,y6,y7, b0 + 1);

  // hoist ALL mask reads (tiny, mostly L2-hot) off the loop critical path
  int mhv0 = 0, mhv1 = 0, mhv2 = 0, mhv3 = 0;
  if (lane < 8) {
    int h = w * 8 + lane;
    mhv0 = read_mask(mask_hist_v, (b0 + 0) * NH + h, mode);
    mhv1 = read_mask(mask_hist_v, (b0 + 1) * NH + h, mode);
    mhv2 = read_mask(mask_hist_v, (b0 + 2) * NH + h, mode);
    mhv3 = read_mask(mask_hist_v, (b0 + 3) * NH + h, mode);
  }
  unsigned int mcb0 = 0, mcb1 = 0, mcb2 = 0, mcb3 = 0;
  #pragma unroll
  for (int j = 0; j < 8; ++j) {
    int c = w * 8 + j;
    mcb0 |= (unsigned int)read_mask(mask_cand_v, (b0 + 0) * NC + c, mode) << j;
    mcb1 |= (unsigned int)read_mask(mask_cand_v, (b0 + 1) * NC + c, mode) << j;
    mcb2 |= (unsigned int)read_mask(mask_cand_v, (b0 + 2) * NC + c, mode) << j;
    mcb3 |= (unsigned int)read_mask(mask_cand_v, (b0 + 3) * NC + c, mode) << j;
  }

  PROC(x0,x1,x2,x3,x4,x5,x6,x7, b0 + 0, mhv0, mcb0);   // x regs free after
  LOAD8(x0,x1,x2,x3,x4,x5,x6,x7, b0 + 2);              // prefetch 1-ahead
  PROC(y0,y1,y2,y3,y4,y5,y6,y7, b0 + 1, mhv1, mcb1);
  LOAD8(y0,y1,y2,y3,y4,y5,y6,y7, b0 + 3);
  PROC(x0,x1,x2,x3,x4,x5,x6,x7, b0 + 2, mhv2, mcb2);
  PROC(y0,y1,y2,y3,y4,y5,y6,y7, b0 + 3, mhv3, mcb3);
}

extern "C" void kernel_launch(void* const* d_in, const int* in_sizes, int n_in,
                              void* d_out, int out_size, void* d_ws, size_t ws_size,
                              hipStream_t stream) {
  (void)in_sizes; (void)n_in; (void)out_size;
  // inputs: 0 cand [B,C,D] (UNUSED — softmax shift-invariance kills the
  // candidate term), 1 hist [B,H,D], 2 mask_cand, 3 mask_hist,
  // 4 W1 [HID,2D], 5 b1 (unused), 6 W2 [1,HID], 7 b2 (unused)
  const float* hist = (const float*)d_in[1];
  const void*  mask_cand = d_in[2];
  const void*  mask_hist = d_in[3];
  const float* W1 = (const float*)d_in[4];
  const float* W2 = (const float*)d_in[6];
  float* ws = (float*)d_ws;
  float* out = (float*)d_out;

  if (ws_size >= (size_t)(WS_PART_OFF + 64 * ND) * sizeof(float)) {
    precompute_p1<<<64, 256, 0, stream>>>(W1, W2, ws);
    precompute_p2<<<1, 256, 0, stream>>>(
        (const unsigned int*)mask_cand, (const unsigned int*)mask_hist, ws);
  } else {
    precompute_fallback<<<1, 1024, 0, stream>>>(
        W1, W2, (const unsigned int*)mask_cand, (const unsigned int*)mask_hist, ws);
  }
  fused4_kernel<<<NB / 4, 512, 0, stream>>>(hist, mask_cand, mask_hist, ws, out);
}

// Round 12
// 40.003 us; speedup vs baseline: 1.1520x; 1.1520x over previous
//
#include <hip/hip_runtime.h>
#include <math.h>

#define NB 1024
#define NC 64
#define NH 64
#define ND 256
#define NHID 256

typedef float f4 __attribute__((ext_vector_type(4)));

// ws layout (floats): [0..255] = v_h, [256] = mask mode (int),
// [1024 .. 1024+64*256) = P1 partials (needs ws >= 69,632 B)
#define WS_PART_OFF 1024

// mask storage modes: 0 = int32, 1 = byte (bool), 2 = float32
__device__ __forceinline__ bool read_mask(const void* m, int idx, int mode) {
  if (mode == 2) return ((const float*)m)[idx] != 0.0f;
  if (mode == 1) return ((const unsigned char*)m)[idx] != 0;
  return ((const int*)m)[idx] != 0;
}

__device__ __forceinline__ void detect_mode(const unsigned int* mask_cand,
                                            const unsigned int* mask_hist,
                                            int* dst) {
  int sawf = 0; unsigned int big = 0;
  for (int i = 0; i < 32; ++i) {
    unsigned int a = mask_hist[i], b = mask_cand[i];
    if (a == 0x3f800000u || b == 0x3f800000u) sawf = 1;
    if ((a > 1u && a != 0x3f800000u) || (b > 1u && b != 0x3f800000u)) big = 1;
  }
  *dst = sawf ? 2 : (big ? 1 : 0);
}

__device__ __forceinline__ float dot4(f4 a, f4 b) {
  return fmaf(a.x, b.x, fmaf(a.y, b.y, fmaf(a.z, b.z, a.w * b.w)));
}

#define BFLY(p) { p += __shfl_xor(p, 32); p += __shfl_xor(p, 16); p += __shfl_xor(p, 8); \
                  p += __shfl_xor(p, 4);  p += __shfl_xor(p, 2);  p += __shfl_xor(p, 1); }

// ---- P1: 64 blocks x 256 threads: partial v_h over 4 j-rows each ----
__global__ __launch_bounds__(256) void precompute_p1(
    const float* __restrict__ W1, const float* __restrict__ W2,
    float* __restrict__ ws)
{
  const int g = blockIdx.x;
  const int d = threadIdx.x;
  float acc = 0.f;
  #pragma unroll
  for (int jj = 0; jj < 4; ++jj) {
    int j = g * 4 + jj;
    acc = fmaf(W1[(size_t)j * (2 * ND) + ND + d], W2[j], acc);
  }
  ws[WS_PART_OFF + g * ND + d] = acc;
}

// ---- P2: 1 block x 256 threads: reduce partials, detect mask mode ----
__global__ __launch_bounds__(256) void precompute_p2(
    const unsigned int* __restrict__ mask_cand,
    const unsigned int* __restrict__ mask_hist,
    float* __restrict__ ws)
{
  const int d = threadIdx.x;
  float acc = 0.f;
  #pragma unroll 8
  for (int g = 0; g < 64; ++g) acc += ws[WS_PART_OFF + g * ND + d];
  ws[d] = acc;
  if (d == 0) detect_mode(mask_cand, mask_hist, (int*)ws + ND);
}

// ---- fallback single-block precompute (small ws) ----
__global__ __launch_bounds__(1024) void precompute_fallback(
    const float* __restrict__ W1, const float* __restrict__ W2,
    const unsigned int* __restrict__ mask_cand,
    const unsigned int* __restrict__ mask_hist,
    float* __restrict__ ws)
{
  __shared__ float w2_lds[NHID];
  __shared__ float partial[4][ND];
  int t = threadIdx.x;
  if (t < NHID) w2_lds[t] = W2[t];
  __syncthreads();
  int d = t & (ND - 1);
  int g = t >> 8;
  float acc = 0.f;
  #pragma unroll 8
  for (int j = g * 64; j < g * 64 + 64; ++j)
    acc = fmaf(W1[(size_t)j * (2 * ND) + ND + d], w2_lds[j], acc);
  partial[g][d] = acc;
  __syncthreads();
  if (t < ND)
    ws[t] = partial[0][t] + partial[1][t] + partial[2][t] + partial[3][t];
  if (t == 0) detect_mode(mask_cand, mask_hist, (int*)ws + ND);
}

// Load 8 consecutive rows (h0..h0+7) as f4 per lane: 8 x 1 KB contiguous.
#define LOADB(R0,R1,R2,R3,R4,R5,R6,R7, H0)                                     \
  R0 = hp4[((H0) + 0) * 64 + lane]; R1 = hp4[((H0) + 1) * 64 + lane];          \
  R2 = hp4[((H0) + 2) * 64 + lane]; R3 = hp4[((H0) + 3) * 64 + lane];          \
  R4 = hp4[((H0) + 4) * 64 + lane]; R5 = hp4[((H0) + 5) * 64 + lane];          \
  R6 = hp4[((H0) + 6) * 64 + lane]; R7 = hp4[((H0) + 7) * 64 + lane];

// Online-softmax batch update over 8 rows (flash-attention style, all lanes
// redundantly carry the scalar state m,s; acc is this lane's 4 output cols).
#define PROCB(R0,R1,R2,R3,R4,R5,R6,R7, H0)                                     \
  {                                                                            \
    float p0 = dot4(R0, vhq), p1 = dot4(R1, vhq), p2 = dot4(R2, vhq),          \
          p3 = dot4(R3, vhq), p4 = dot4(R4, vhq), p5 = dot4(R5, vhq),          \
          p6 = dot4(R6, vhq), p7 = dot4(R7, vhq);                              \
    BFLY(p0) BFLY(p1) BFLY(p2) BFLY(p3) BFLY(p4) BFLY(p5) BFLY(p6) BFLY(p7)    \
    p0 = ((mh >> ((H0) + 0)) & 1) ? p0 : -3.0e38f;                             \
    p1 = ((mh >> ((H0) + 1)) & 1) ? p1 : -3.0e38f;                             \
    p2 = ((mh >> ((H0) + 2)) & 1) ? p2 : -3.0e38f;                             \
    p3 = ((mh >> ((H0) + 3)) & 1) ? p3 : -3.0e38f;                             \
    p4 = ((mh >> ((H0) + 4)) & 1) ? p4 : -3.0e38f;                             \
    p5 = ((mh >> ((H0) + 5)) & 1) ? p5 : -3.0e38f;                             \
    p6 = ((mh >> ((H0) + 6)) & 1) ? p6 : -3.0e38f;                             \
    p7 = ((mh >> ((H0) + 7)) & 1) ? p7 : -3.0e38f;                             \
    float pm = fmaxf(fmaxf(fmaxf(p0, p1), fmaxf(p2, p3)),                      \
                     fmaxf(fmaxf(p4, p5), fmaxf(p6, p7)));                     \
    float mn = fmaxf(mrun, pm);                                                \
    float sc = expf(mrun - mn);                                                \
    float e0 = expf(p0 - mn), e1 = expf(p1 - mn), e2 = expf(p2 - mn),          \
          e3 = expf(p3 - mn), e4 = expf(p4 - mn), e5 = expf(p5 - mn),          \
          e6 = expf(p6 - mn), e7 = expf(p7 - mn);                              \
    srun = srun * sc + ((e0 + e1) + (e2 + e3)) + ((e4 + e5) + (e6 + e7));      \
    acc = acc * sc;                                                            \
    acc += e0 * R0; acc += e1 * R1; acc += e2 * R2; acc += e3 * R3;            \
    acc += e4 * R4; acc += e5 * R5; acc += e6 * R6; acc += e7 * R7;            \
    mrun = mn;                                                                 \
  }

// ---- main: ONE WAVE PER BATCH b; no barriers, no LDS, no inter-wave
// coupling. Flash-style online softmax: hist read exactly once as a 64 x 1KB
// load stream (double-buffered 8-row batches), then a 64 x 1KB contiguous
// masked store sweep. 256 blocks x 256 thr = 1024 independent wave-streams
// (the fill-kernel regime: few waves, each a long continuous stream). ----
__global__ __launch_bounds__(256) void flash_kernel(
    const float* __restrict__ hist,
    const void* __restrict__ mask_cand_v,
    const void* __restrict__ mask_hist_v,
    const float* __restrict__ ws,
    float* __restrict__ out)
{
  const int t = threadIdx.x, lane = t & 63, w = t >> 6;
  const int b = blockIdx.x * 4 + w;

  const int mode = ((const int*)ws)[ND];
  const f4* hp4 = reinterpret_cast<const f4*>(hist) + (size_t)b * 4096;
  const f4 vhq = reinterpret_cast<const f4*>(ws)[lane];   // 1 KB, L1-hot

  // per-wave 64-bit masks via ballot (one coalesced lane-read each)
  const unsigned long long mh =
      __ballot(read_mask(mask_hist_v, b * NH + lane, mode));
  const unsigned long long mc =
      __ballot(read_mask(mask_cand_v, b * NC + lane, mode));

  float mrun = -3.0e38f, srun = 0.f;
  f4 acc = {0.f, 0.f, 0.f, 0.f};
  f4 x0, x1, x2, x3, x4, x5, x6, x7;
  f4 y0, y1, y2, y3, y4, y5, y6, y7;

  // software pipeline: loads of batch i+1 issue before compute of batch i
  LOADB(x0,x1,x2,x3,x4,x5,x6,x7, 0)
  LOADB(y0,y1,y2,y3,y4,y5,y6,y7, 8)
  PROCB(x0,x1,x2,x3,x4,x5,x6,x7, 0)
  LOADB(x0,x1,x2,x3,x4,x5,x6,x7, 16)
  PROCB(y0,y1,y2,y3,y4,y5,y6,y7, 8)
  LOADB(y0,y1,y2,y3,y4,y5,y6,y7, 24)
  PROCB(x0,x1,x2,x3,x4,x5,x6,x7, 16)
  LOADB(x0,x1,x2,x3,x4,x5,x6,x7, 32)
  PROCB(y0,y1,y2,y3,y4,y5,y6,y7, 24)
  LOADB(y0,y1,y2,y3,y4,y5,y6,y7, 40)
  PROCB(x0,x1,x2,x3,x4,x5,x6,x7, 32)
  LOADB(x0,x1,x2,x3,x4,x5,x6,x7, 48)
  PROCB(y0,y1,y2,y3,y4,y5,y6,y7, 40)
  LOADB(y0,y1,y2,y3,y4,y5,y6,y7, 56)
  PROCB(x0,x1,x2,x3,x4,x5,x6,x7, 48)
  PROCB(y0,y1,y2,y3,y4,y5,y6,y7, 56)

  // normalize and broadcast-store 64 rows (64 x 1 KB contiguous sweep)
  const f4 uv = acc * (1.0f / srun);
  const f4 zero = {0.f, 0.f, 0.f, 0.f};
  f4* ob4 = reinterpret_cast<f4*>(out) + (size_t)b * 4096;
  #pragma unroll
  for (int c = 0; c < 64; ++c)
    ob4[c * 64 + lane] = ((mc >> c) & 1ull) ? uv : zero;
}

extern "C" void kernel_launch(void* const* d_in, const int* in_sizes, int n_in,
                              void* d_out, int out_size, void* d_ws, size_t ws_size,
                              hipStream_t stream) {
  (void)in_sizes; (void)n_in; (void)out_size;
  // inputs: 0 cand [B,C,D] (UNUSED — softmax shift-invariance kills the
  // candidate term), 1 hist [B,H,D], 2 mask_cand, 3 mask_hist,
  // 4 W1 [HID,2D], 5 b1 (unused), 6 W2 [1,HID], 7 b2 (unused)
  const float* hist = (const float*)d_in[1];
  const void*  mask_cand = d_in[2];
  const void*  mask_hist = d_in[3];
  const float* W1 = (const float*)d_in[4];
  const float* W2 = (const float*)d_in[6];
  float* ws = (float*)d_ws;
  float* out = (float*)d_out;

  if (ws_size >= (size_t)(WS_PART_OFF + 64 * ND) * sizeof(float)) {
    precompute_p1<<<64, 256, 0, stream>>>(W1, W2, ws);
    precompute_p2<<<1, 256, 0, stream>>>(
        (const unsigned int*)mask_cand, (const unsigned int*)mask_hist, ws);
  } else {
    precompute_fallback<<<1, 1024, 0, stream>>>(
        W1, W2, (const unsigned int*)mask_cand, (const unsigned int*)mask_hist, ws);
  }
  flash_kernel<<<NB / 4, 256, 0, stream>>>(hist, mask_cand, mask_hist, ws, out);
}